// Round 4
// baseline (513.585 us; speedup 1.0000x reference)
//
#include <hip/hip_runtime.h>
#include <stdint.h>

#define NN 50000
#define NE 800000
#define DD 128
#define NL 3

typedef __attribute__((ext_vector_type(8))) short short8;
typedef __attribute__((ext_vector_type(4))) float f32x4;

// ---------- bf16 helpers ----------
__device__ __forceinline__ float b2f(unsigned short u){
  union { unsigned int i; float f; } v; v.i = ((unsigned int)u) << 16; return v.f;
}
__device__ __forceinline__ unsigned short f2b(float f){
  union { float f; unsigned int i; } v; v.f = f;
  unsigned int r = 0x7FFFu + ((v.i >> 16) & 1u);
  return (unsigned short)((v.i + r) >> 16);
}

// ---------- CSR build ----------
__global__ void k_count(const int* __restrict__ dst, int* __restrict__ counts){
  int e = blockIdx.x * 256 + threadIdx.x;
  if (e < NE) atomicAdd(&counts[dst[e]], 1);
}

__global__ void k_scan1(const int* __restrict__ counts, int* __restrict__ offs,
                        int* __restrict__ bsum){
  __shared__ int s[256];
  int t = threadIdx.x; int i = blockIdx.x * 256 + t;
  int v = (i < NN) ? counts[i] : 0;
  s[t] = v; __syncthreads();
  for (int d = 1; d < 256; d <<= 1){
    int x = (t >= d) ? s[t - d] : 0;
    __syncthreads();
    s[t] += x;
    __syncthreads();
  }
  if (i < NN) offs[i] = s[t] - v;
  if (t == 255) bsum[blockIdx.x] = s[255];
}

__global__ void k_scan2(int* __restrict__ bsum, int nblk){
  __shared__ int s[256];
  int t = threadIdx.x;
  int v = (t < nblk) ? bsum[t] : 0;
  s[t] = v; __syncthreads();
  for (int d = 1; d < 256; d <<= 1){
    int x = (t >= d) ? s[t - d] : 0;
    __syncthreads();
    s[t] += x;
    __syncthreads();
  }
  if (t < nblk) bsum[t] = s[t] - v;
}

__global__ void k_scan3(int* __restrict__ offs, const int* __restrict__ bsum,
                        int* __restrict__ cursor){
  int i = blockIdx.x * 256 + threadIdx.x;
  if (i < NN){
    int o = offs[i] + bsum[blockIdx.x];
    offs[i] = o;
    cursor[i] = o;
  }
}

__global__ void k_fill(const int* __restrict__ src, const int* __restrict__ dst,
                       int* __restrict__ cursor, int* __restrict__ csr_src){
  int e = blockIdx.x * 256 + threadIdx.x;
  if (e < NE){
    int d = dst[e];
    int p = atomicAdd(&cursor[d], 1);
    csr_src[p] = src[e];
  }
}

// ---------- prep: W -> transposed hi/lo bf16 split ----------
__global__ void k_prep_w(const float* __restrict__ W1, const float* __restrict__ W2,
    unsigned short* __restrict__ Wthi, unsigned short* __restrict__ Wtlo){
  int idx = blockIdx.x * 256 + threadIdx.x;   // 98304 = 6*128*128
  int mat = idx >> 14;
  int rem = idx & 16383;
  int k = rem >> 7, j = rem & 127;
  int layer = mat >> 1, which = mat & 1;
  const float* srcW = which ? W2 : W1;
  float w = srcW[layer * 16384 + k * DD + j];
  unsigned short hi = f2b(w);
  Wthi[mat * 16384 + j * DD + k] = hi;
  Wtlo[mat * 16384 + j * DD + k] = f2b(w - b2f(hi));
}

// ---------- prep: fold bias+BN into per-col scale/shift ----------
__global__ void k_prep_bn(const float* __restrict__ b1, const float* __restrict__ b2,
    const float* __restrict__ g, const float* __restrict__ be,
    const float* __restrict__ rm, const float* __restrict__ rv,
    float* __restrict__ sc, float* __restrict__ sh){
  int idx = blockIdx.x * 256 + threadIdx.x;   // 768 = 3*2*128
  if (idx >= NL * 2 * DD) return;
  int j = idx & 127;
  int w = (idx >> 7) & 1;
  int l = idx >> 8;
  int p = (l * 2 + w) * DD + j;
  float s = g[p] * rsqrtf(rv[p] + 1e-5f);
  float bias = w ? b2[l * DD + j] : b1[l * DD + j];
  sc[p] = s;
  sh[p] = fmaf(bias - rm[p], s, be[p]);
}

// ---------- x fp32 -> hi/lo bf16 split ----------
__global__ void k_cvt(const float* __restrict__ x,
    unsigned short* __restrict__ hi, unsigned short* __restrict__ lo){
  int i = blockIdx.x * 256 + threadIdx.x;     // 8-elem units; grid covers NN*DD/8
  float4 a = ((const float4*)x)[2 * i];
  float4 b = ((const float4*)x)[2 * i + 1];
  float v[8] = {a.x, a.y, a.z, a.w, b.x, b.y, b.z, b.w};
  short8 h8, l8;
  #pragma unroll
  for (int c = 0; c < 8; ++c){
    unsigned short h = f2b(v[c]);
    h8[c] = (short)h; l8[c] = (short)f2b(v[c] - b2f(h));
  }
  ((short8*)hi)[i] = h8;
  ((short8*)lo)[i] = l8;
}

// ---------- aggregate: A = (Shi+Slo)[v] + sum_nbr Shi[src] ; write hi/lo split ----------
__global__ __launch_bounds__(256) void k_agg(
    const unsigned short* __restrict__ Shi, const unsigned short* __restrict__ Slo,
    const int* __restrict__ offs, const int* __restrict__ counts,
    const int* __restrict__ csr_src,
    unsigned short* __restrict__ Ahi, unsigned short* __restrict__ Alo){
  int t = blockIdx.x * 256 + threadIdx.x;
  int row = t >> 4;                // 16 rows / block; grid 3125 covers exactly NN
  int l = t & 15;
  const short8* H = (const short8*)Shi;   // 16 x short8 per row
  const short8* L = (const short8*)Slo;
  int idx = row * 16 + l;
  short8 s_h = H[idx]; short8 s_l = L[idx];
  float acc[8];
  #pragma unroll
  for (int i = 0; i < 8; ++i)
    acc[i] = b2f((unsigned short)s_h[i]) + b2f((unsigned short)s_l[i]);

  int e = offs[row];
  int end = e + counts[row];
  for (; e + 4 <= end; e += 4){
    int s0 = csr_src[e], s1 = csr_src[e+1], s2 = csr_src[e+2], s3 = csr_src[e+3];
    short8 g0 = H[s0*16 + l], g1 = H[s1*16 + l], g2 = H[s2*16 + l], g3 = H[s3*16 + l];
    #pragma unroll
    for (int i = 0; i < 8; ++i){
      acc[i] += b2f((unsigned short)g0[i]) + b2f((unsigned short)g1[i])
              + b2f((unsigned short)g2[i]) + b2f((unsigned short)g3[i]);
    }
  }
  for (; e < end; ++e){
    short8 g0 = H[csr_src[e]*16 + l];
    #pragma unroll
    for (int i = 0; i < 8; ++i) acc[i] += b2f((unsigned short)g0[i]);
  }

  short8 oh, ol;
  #pragma unroll
  for (int i = 0; i < 8; ++i){
    unsigned short h = f2b(acc[i]);
    oh[i] = (short)h; ol[i] = (short)f2b(acc[i] - b2f(h));
  }
  ((short8*)Ahi)[idx] = oh;
  ((short8*)Alo)[idx] = ol;
}

// ---------- LDS-free split-bf16 MFMA GEMM + BN + ReLU ----------
// Wave: 16 rows x 64 cols. Block 256 = 4 waves = 32 rows x 128 cols.
// A,B fragments are single 16B loads from pre-split global bf16 arrays.
template<int LAST>
__global__ __launch_bounds__(256) void k_gemm(
    const unsigned short* __restrict__ Ahi, const unsigned short* __restrict__ Alo,
    const unsigned short* __restrict__ Wthi, const unsigned short* __restrict__ Wtlo,
    const float* __restrict__ sc, const float* __restrict__ sh,
    unsigned short* __restrict__ Ohi, unsigned short* __restrict__ Olo,
    float* __restrict__ Of)
{
  int t = threadIdx.x;
  int wave = t >> 6, lane = t & 63, l16 = lane & 15, q = lane >> 4;
  int rowbase = blockIdx.x * 32 + (wave >> 1) * 16;
  int colbase = (wave & 1) * 64;

  int ar = rowbase + l16; if (ar > NN - 1) ar = NN - 1;
  const short8* AH = (const short8*)Ahi;   // [row][16]
  const short8* AL = (const short8*)Alo;
  const short8* BH = (const short8*)Wthi;  // [j][16]
  const short8* BL = (const short8*)Wtlo;

  f32x4 acc[4];
  #pragma unroll
  for (int ct = 0; ct < 4; ++ct) acc[ct] = (f32x4){0.f, 0.f, 0.f, 0.f};

  #pragma unroll
  for (int kc = 0; kc < 4; ++kc){
    short8 ah = AH[ar * 16 + kc * 4 + q];
    short8 al = AL[ar * 16 + kc * 4 + q];
    #pragma unroll
    for (int ct = 0; ct < 4; ++ct){
      int wr = colbase + ct * 16 + l16;
      short8 bh = BH[wr * 16 + kc * 4 + q];
      short8 bl = BL[wr * 16 + kc * 4 + q];
      acc[ct] = __builtin_amdgcn_mfma_f32_16x16x32_bf16(ah, bh, acc[ct], 0, 0, 0);
      acc[ct] = __builtin_amdgcn_mfma_f32_16x16x32_bf16(ah, bl, acc[ct], 0, 0, 0);
      acc[ct] = __builtin_amdgcn_mfma_f32_16x16x32_bf16(al, bh, acc[ct], 0, 0, 0);
    }
  }

  #pragma unroll
  for (int ct = 0; ct < 4; ++ct){
    int col = colbase + ct * 16 + l16;
    float s = sc[col], b = sh[col];
    #pragma unroll
    for (int r = 0; r < 4; ++r){
      int row = rowbase + q * 4 + r;     // C/D layout: row=(lane>>4)*4+reg
      if (row < NN){
        float v = fmaxf(fmaf(acc[ct][r], s, b), 0.f);
        if (LAST){
          Of[row * DD + col] = v;
        } else {
          unsigned short hv = f2b(v);
          Ohi[row * DD + col] = hv;
          Olo[row * DD + col] = f2b(v - b2f(hv));
        }
      }
    }
  }
}

// ---------- launch ----------
extern "C" void kernel_launch(void* const* d_in, const int* in_sizes, int n_in,
                              void* d_out, int out_size, void* d_ws, size_t ws_size,
                              hipStream_t stream) {
  const float* x  = (const float*)d_in[0];
  const int* ei   = (const int*)d_in[1];
  const float* W1 = (const float*)d_in[2];
  const float* b1 = (const float*)d_in[3];
  const float* W2 = (const float*)d_in[4];
  const float* b2 = (const float*)d_in[5];
  const float* g  = (const float*)d_in[6];
  const float* be = (const float*)d_in[7];
  const float* rm = (const float*)d_in[8];
  const float* rv = (const float*)d_in[9];

  const int* src = ei;
  const int* dst = ei + NE;

  char* w = (char*)d_ws;
  const size_t HB = (size_t)NN * DD * sizeof(unsigned short);  // 12.8 MB
  unsigned short* Shi = (unsigned short*)w; w += HB;  // h (self+gather table), hi
  unsigned short* Slo = (unsigned short*)w; w += HB;  // h lo
  unsigned short* Ahi = (unsigned short*)w; w += HB;  // agg out hi
  unsigned short* Alo = (unsigned short*)w; w += HB;
  unsigned short* Hhi = (unsigned short*)w; w += HB;  // gemm1 out hi
  unsigned short* Hlo = (unsigned short*)w; w += HB;
  unsigned short* Wthi = (unsigned short*)w; w += 6 * 16384 * sizeof(unsigned short);
  unsigned short* Wtlo = (unsigned short*)w; w += 6 * 16384 * sizeof(unsigned short);
  float* scv = (float*)w; w += NL * 2 * DD * sizeof(float);
  float* shv = (float*)w; w += NL * 2 * DD * sizeof(float);
  int* counts = (int*)w;  w += 200192;
  int* offs   = (int*)w;  w += 200192;
  int* cursor = (int*)w;  w += 200192;
  int* bsum   = (int*)w;  w += 1024;
  int* csr_src= (int*)w;  w += (size_t)NE * sizeof(int);

  const int NBLK = (NN + 255) / 256;   // 196

  // CSR build
  hipMemsetAsync(counts, 0, (size_t)NN * sizeof(int), stream);
  k_count<<<(NE + 255) / 256, 256, 0, stream>>>(dst, counts);
  k_scan1<<<NBLK, 256, 0, stream>>>(counts, offs, bsum);
  k_scan2<<<1, 256, 0, stream>>>(bsum, NBLK);
  k_scan3<<<NBLK, 256, 0, stream>>>(offs, bsum, cursor);
  k_fill<<<(NE + 255) / 256, 256, 0, stream>>>(src, dst, cursor, csr_src);

  // weight / BN prep + x split
  k_prep_w<<<384, 256, 0, stream>>>(W1, W2, Wthi, Wtlo);
  k_prep_bn<<<3, 256, 0, stream>>>(b1, b2, g, be, rm, rv, scv, shv);
  k_cvt<<<NN * DD / 8 / 256, 256, 0, stream>>>(x, Shi, Slo);

  const int AGG_BLOCKS  = NN * 16 / 256;        // 3125
  const int GEMM_BLOCKS = (NN + 31) / 32;       // 1563

  for (int i = 0; i < NL; ++i){
    k_agg<<<AGG_BLOCKS, 256, 0, stream>>>(Shi, Slo, offs, counts, csr_src, Ahi, Alo);

    const unsigned short* W1t_hi = Wthi + (size_t)(i * 2 + 0) * 16384;
    const unsigned short* W1t_lo = Wtlo + (size_t)(i * 2 + 0) * 16384;
    const unsigned short* W2t_hi = Wthi + (size_t)(i * 2 + 1) * 16384;
    const unsigned short* W2t_lo = Wtlo + (size_t)(i * 2 + 1) * 16384;
    const float* sc1 = scv + (size_t)(i * 2 + 0) * DD;
    const float* sh1 = shv + (size_t)(i * 2 + 0) * DD;
    const float* sc2 = scv + (size_t)(i * 2 + 1) * DD;
    const float* sh2 = shv + (size_t)(i * 2 + 1) * DD;

    k_gemm<0><<<GEMM_BLOCKS, 256, 0, stream>>>(Ahi, Alo, W1t_hi, W1t_lo,
        sc1, sh1, Hhi, Hlo, (float*)nullptr);

    if (i == NL - 1){
      k_gemm<1><<<GEMM_BLOCKS, 256, 0, stream>>>(Hhi, Hlo, W2t_hi, W2t_lo,
          sc2, sh2, (unsigned short*)nullptr, (unsigned short*)nullptr, (float*)d_out);
    } else {
      k_gemm<0><<<GEMM_BLOCKS, 256, 0, stream>>>(Hhi, Hlo, W2t_hi, W2t_lo,
          sc2, sh2, Shi, Slo, (float*)nullptr);
    }
  }
}

// Round 5
// 458.454 us; speedup vs baseline: 1.1203x; 1.1203x over previous
//
#include <hip/hip_runtime.h>
#include <stdint.h>

#define NN 50000
#define NE 800000
#define E4 200000
#define DD 128
#define NL 3

typedef __attribute__((ext_vector_type(8))) short short8;
typedef __attribute__((ext_vector_type(4))) float f32x4;

// ---------- bf16 helpers ----------
__device__ __forceinline__ float b2f(unsigned short u){
  union { unsigned int i; float f; } v; v.i = ((unsigned int)u) << 16; return v.f;
}
__device__ __forceinline__ unsigned short f2b(float f){
  union { float f; unsigned int i; } v; v.f = f;
  unsigned int r = 0x7FFFu + ((v.i >> 16) & 1u);
  return (unsigned short)((v.i + r) >> 16);
}

// ---------- CSR build ----------
__global__ void k_count(const int* __restrict__ dst, int* __restrict__ counts){
  int t = blockIdx.x * 256 + threadIdx.x;
  if (t >= E4) return;
  int d0 = dst[t];
  int d1 = dst[t + E4];
  int d2 = dst[t + 2*E4];
  int d3 = dst[t + 3*E4];
  atomicAdd(&counts[d0], 1);
  atomicAdd(&counts[d1], 1);
  atomicAdd(&counts[d2], 1);
  atomicAdd(&counts[d3], 1);
}

__global__ void k_scan1(const int* __restrict__ counts, int* __restrict__ offs,
                        int* __restrict__ bsum){
  __shared__ int s[256];
  int t = threadIdx.x; int i = blockIdx.x * 256 + t;
  int v = (i < NN) ? counts[i] : 0;
  s[t] = v; __syncthreads();
  for (int d = 1; d < 256; d <<= 1){
    int x = (t >= d) ? s[t - d] : 0;
    __syncthreads();
    s[t] += x;
    __syncthreads();
  }
  if (i < NN) offs[i] = s[t] - v;
  if (t == 255) bsum[blockIdx.x] = s[255];
}

__global__ void k_scan2(int* __restrict__ bsum, int nblk){
  __shared__ int s[256];
  int t = threadIdx.x;
  int v = (t < nblk) ? bsum[t] : 0;
  s[t] = v; __syncthreads();
  for (int d = 1; d < 256; d <<= 1){
    int x = (t >= d) ? s[t - d] : 0;
    __syncthreads();
    s[t] += x;
    __syncthreads();
  }
  if (t < nblk) bsum[t] = s[t] - v;
}

__global__ void k_scan3(int* __restrict__ offs, const int* __restrict__ bsum,
                        int* __restrict__ cursor){
  int i = blockIdx.x * 256 + threadIdx.x;
  if (i < NN){
    int o = offs[i] + bsum[blockIdx.x];
    offs[i] = o;
    cursor[i] = o;
  }
}

__global__ void k_fill(const int* __restrict__ src, const int* __restrict__ dst,
                       int* __restrict__ cursor, int* __restrict__ csr_src){
  int t = blockIdx.x * 256 + threadIdx.x;
  if (t >= E4) return;
  int d0 = dst[t];
  int d1 = dst[t + E4];
  int d2 = dst[t + 2*E4];
  int d3 = dst[t + 3*E4];
  int s0 = src[t];
  int s1 = src[t + E4];
  int s2 = src[t + 2*E4];
  int s3 = src[t + 3*E4];
  int p0 = atomicAdd(&cursor[d0], 1);
  int p1 = atomicAdd(&cursor[d1], 1);
  int p2 = atomicAdd(&cursor[d2], 1);
  int p3 = atomicAdd(&cursor[d3], 1);
  csr_src[p0] = s0;
  csr_src[p1] = s1;
  csr_src[p2] = s2;
  csr_src[p3] = s3;
}

// ---------- prep: W -> transposed hi/lo bf16 split ----------
__global__ void k_prep_w(const float* __restrict__ W1, const float* __restrict__ W2,
    unsigned short* __restrict__ Wthi, unsigned short* __restrict__ Wtlo){
  int idx = blockIdx.x * 256 + threadIdx.x;   // 98304 = 6*128*128
  int mat = idx >> 14;
  int rem = idx & 16383;
  int k = rem >> 7, j = rem & 127;
  int layer = mat >> 1, which = mat & 1;
  const float* srcW = which ? W2 : W1;
  float w = srcW[layer * 16384 + k * DD + j];
  unsigned short hi = f2b(w);
  Wthi[mat * 16384 + j * DD + k] = hi;
  Wtlo[mat * 16384 + j * DD + k] = f2b(w - b2f(hi));
}

// ---------- prep: fold bias+BN into per-col scale/shift ----------
__global__ void k_prep_bn(const float* __restrict__ b1, const float* __restrict__ b2,
    const float* __restrict__ g, const float* __restrict__ be,
    const float* __restrict__ rm, const float* __restrict__ rv,
    float* __restrict__ sc, float* __restrict__ sh){
  int idx = blockIdx.x * 256 + threadIdx.x;   // 768 = 3*2*128
  if (idx >= NL * 2 * DD) return;
  int j = idx & 127;
  int w = (idx >> 7) & 1;
  int l = idx >> 8;
  int p = (l * 2 + w) * DD + j;
  float s = g[p] * rsqrtf(rv[p] + 1e-5f);
  float bias = w ? b2[l * DD + j] : b1[l * DD + j];
  sc[p] = s;
  sh[p] = fmaf(bias - rm[p], s, be[p]);
}

// ---------- x fp32 -> hi/lo bf16 split ----------
__global__ void k_cvt(const float* __restrict__ x,
    unsigned short* __restrict__ hi, unsigned short* __restrict__ lo){
  int i = blockIdx.x * 256 + threadIdx.x;     // 8-elem units; grid covers NN*DD/8
  float4 a = ((const float4*)x)[2 * i];
  float4 b = ((const float4*)x)[2 * i + 1];
  float v[8] = {a.x, a.y, a.z, a.w, b.x, b.y, b.z, b.w};
  short8 h8, l8;
  #pragma unroll
  for (int c = 0; c < 8; ++c){
    unsigned short h = f2b(v[c]);
    h8[c] = (short)h; l8[c] = (short)f2b(v[c] - b2f(h));
  }
  ((short8*)hi)[i] = h8;
  ((short8*)lo)[i] = l8;
}

// ---------- aggregate: A = (Shi+Slo)[v] + sum_nbr Shi[src] ; write hi/lo split ----------
__global__ __launch_bounds__(256) void k_agg(
    const unsigned short* __restrict__ Shi, const unsigned short* __restrict__ Slo,
    const int* __restrict__ offs, const int* __restrict__ counts,
    const int* __restrict__ csr_src,
    unsigned short* __restrict__ Ahi, unsigned short* __restrict__ Alo){
  int t = blockIdx.x * 256 + threadIdx.x;
  int row = t >> 4;                // 16 rows / block; grid 3125 covers exactly NN
  int l = t & 15;
  const short8* H = (const short8*)Shi;   // 16 x short8 per row
  const short8* L = (const short8*)Slo;
  int idx = row * 16 + l;
  short8 s_h = H[idx]; short8 s_l = L[idx];
  float acc[8];
  #pragma unroll
  for (int i = 0; i < 8; ++i)
    acc[i] = b2f((unsigned short)s_h[i]) + b2f((unsigned short)s_l[i]);

  int e = offs[row];
  int end = e + counts[row];
  for (; e + 4 <= end; e += 4){
    int s0 = csr_src[e], s1 = csr_src[e+1], s2 = csr_src[e+2], s3 = csr_src[e+3];
    short8 g0 = H[s0*16 + l], g1 = H[s1*16 + l], g2 = H[s2*16 + l], g3 = H[s3*16 + l];
    #pragma unroll
    for (int i = 0; i < 8; ++i){
      acc[i] += b2f((unsigned short)g0[i]) + b2f((unsigned short)g1[i])
              + b2f((unsigned short)g2[i]) + b2f((unsigned short)g3[i]);
    }
  }
  for (; e < end; ++e){
    short8 g0 = H[csr_src[e]*16 + l];
    #pragma unroll
    for (int i = 0; i < 8; ++i) acc[i] += b2f((unsigned short)g0[i]);
  }

  short8 oh, ol;
  #pragma unroll
  for (int i = 0; i < 8; ++i){
    unsigned short h = f2b(acc[i]);
    oh[i] = (short)h; ol[i] = (short)f2b(acc[i] - b2f(h));
  }
  ((short8*)Ahi)[idx] = oh;
  ((short8*)Alo)[idx] = ol;
}

// ---------- LDS-free split-bf16 MFMA GEMM + BN + ReLU, v2 ----------
// Block 256 = 4 waves; wave = 32 rows x 64 cols (2 row-tiles, 2x B reuse).
// Epilogue: wave-private LDS staging -> coalesced 16B stores (no barriers).
#define SSTR 72   // LDS tile row stride (ushort or float units); 72*2=144 B (16-aligned)
template<int LAST>
__global__ __launch_bounds__(256) void k_gemm(
    const unsigned short* __restrict__ Ahi, const unsigned short* __restrict__ Alo,
    const unsigned short* __restrict__ Wthi, const unsigned short* __restrict__ Wtlo,
    const float* __restrict__ sc, const float* __restrict__ sh,
    unsigned short* __restrict__ Ohi, unsigned short* __restrict__ Olo,
    float* __restrict__ Of)
{
  __shared__ __align__(16) char smem[4][32 * SSTR * 4];   // 36864 B: per-wave 9216 B
  int t = threadIdx.x;
  int wave = t >> 6, lane = t & 63, l16 = lane & 15, q = lane >> 4;
  int rowbase = blockIdx.x * 64 + (wave >> 1) * 32;
  int colbase = (wave & 1) * 64;

  int ar0 = rowbase + l16;      if (ar0 > NN - 1) ar0 = NN - 1;
  int ar1 = rowbase + 16 + l16; if (ar1 > NN - 1) ar1 = NN - 1;

  const short8* AH = (const short8*)Ahi;   // [row][16]
  const short8* AL = (const short8*)Alo;
  const short8* BH = (const short8*)Wthi;  // [j][16]
  const short8* BL = (const short8*)Wtlo;

  f32x4 acc[2][4];
  #pragma unroll
  for (int rt = 0; rt < 2; ++rt)
    #pragma unroll
    for (int ct = 0; ct < 4; ++ct) acc[rt][ct] = (f32x4){0.f, 0.f, 0.f, 0.f};

  #pragma unroll
  for (int kc = 0; kc < 4; ++kc){
    short8 ah0 = AH[ar0 * 16 + kc * 4 + q];
    short8 al0 = AL[ar0 * 16 + kc * 4 + q];
    short8 ah1 = AH[ar1 * 16 + kc * 4 + q];
    short8 al1 = AL[ar1 * 16 + kc * 4 + q];
    #pragma unroll
    for (int ct = 0; ct < 4; ++ct){
      int wr = colbase + ct * 16 + l16;
      short8 bh = BH[wr * 16 + kc * 4 + q];
      short8 bl = BL[wr * 16 + kc * 4 + q];
      acc[0][ct] = __builtin_amdgcn_mfma_f32_16x16x32_bf16(ah0, bh, acc[0][ct], 0, 0, 0);
      acc[0][ct] = __builtin_amdgcn_mfma_f32_16x16x32_bf16(ah0, bl, acc[0][ct], 0, 0, 0);
      acc[0][ct] = __builtin_amdgcn_mfma_f32_16x16x32_bf16(al0, bh, acc[0][ct], 0, 0, 0);
      acc[1][ct] = __builtin_amdgcn_mfma_f32_16x16x32_bf16(ah1, bh, acc[1][ct], 0, 0, 0);
      acc[1][ct] = __builtin_amdgcn_mfma_f32_16x16x32_bf16(ah1, bl, acc[1][ct], 0, 0, 0);
      acc[1][ct] = __builtin_amdgcn_mfma_f32_16x16x32_bf16(al1, bh, acc[1][ct], 0, 0, 0);
    }
  }

  if (!LAST){
    unsigned short* shh = (unsigned short*)smem[wave];      // 32 x SSTR hi
    unsigned short* shl = shh + 32 * SSTR;                  // 32 x SSTR lo
    #pragma unroll
    for (int rt = 0; rt < 2; ++rt)
      #pragma unroll
      for (int ct = 0; ct < 4; ++ct){
        int colg = colbase + ct * 16 + l16;
        float s = sc[colg], b = sh[colg];
        #pragma unroll
        for (int r = 0; r < 4; ++r){
          int row_l = rt * 16 + q * 4 + r;                  // C/D layout
          float v = fmaxf(fmaf(acc[rt][ct][r], s, b), 0.f);
          unsigned short h = f2b(v);
          shh[row_l * SSTR + ct * 16 + l16] = h;
          shl[row_l * SSTR + ct * 16 + l16] = f2b(v - b2f(h));
        }
      }
    // coalesced read-back + store: 4 iters x (8 rows x 8 lanes/row)
    int rr = lane >> 3, cu = (lane & 7) * 8;
    #pragma unroll
    for (int i = 0; i < 4; ++i){
      int row_l = i * 8 + rr;
      int row_g = rowbase + row_l;
      short8 vh = *(const short8*)&shh[row_l * SSTR + cu];
      short8 vl = *(const short8*)&shl[row_l * SSTR + cu];
      if (row_g < NN){
        *(short8*)&Ohi[row_g * DD + colbase + cu] = vh;
        *(short8*)&Olo[row_g * DD + colbase + cu] = vl;
      }
    }
  } else {
    float* sf = (float*)smem[wave];                         // 32 x SSTR fp32
    #pragma unroll
    for (int rt = 0; rt < 2; ++rt)
      #pragma unroll
      for (int ct = 0; ct < 4; ++ct){
        int colg = colbase + ct * 16 + l16;
        float s = sc[colg], b = sh[colg];
        #pragma unroll
        for (int r = 0; r < 4; ++r){
          int row_l = rt * 16 + q * 4 + r;
          sf[row_l * SSTR + ct * 16 + l16] = fmaxf(fmaf(acc[rt][ct][r], s, b), 0.f);
        }
      }
    int rr = lane >> 4, cf = (lane & 15) * 4;
    #pragma unroll
    for (int i = 0; i < 8; ++i){
      int row_l = i * 4 + rr;
      int row_g = rowbase + row_l;
      float4 v = *(const float4*)&sf[row_l * SSTR + cf];
      if (row_g < NN) *(float4*)&Of[row_g * DD + colbase + cf] = v;
    }
  }
}

// ---------- launch ----------
extern "C" void kernel_launch(void* const* d_in, const int* in_sizes, int n_in,
                              void* d_out, int out_size, void* d_ws, size_t ws_size,
                              hipStream_t stream) {
  const float* x  = (const float*)d_in[0];
  const int* ei   = (const int*)d_in[1];
  const float* W1 = (const float*)d_in[2];
  const float* b1 = (const float*)d_in[3];
  const float* W2 = (const float*)d_in[4];
  const float* b2 = (const float*)d_in[5];
  const float* g  = (const float*)d_in[6];
  const float* be = (const float*)d_in[7];
  const float* rm = (const float*)d_in[8];
  const float* rv = (const float*)d_in[9];

  const int* src = ei;
  const int* dst = ei + NE;

  char* w = (char*)d_ws;
  const size_t HB = (size_t)NN * DD * sizeof(unsigned short);  // 12.8 MB
  unsigned short* Shi = (unsigned short*)w; w += HB;  // h table hi
  unsigned short* Slo = (unsigned short*)w; w += HB;  // h table lo
  unsigned short* Ahi = (unsigned short*)w; w += HB;  // agg out hi
  unsigned short* Alo = (unsigned short*)w; w += HB;
  unsigned short* Hhi = (unsigned short*)w; w += HB;  // gemm1 out hi
  unsigned short* Hlo = (unsigned short*)w; w += HB;
  unsigned short* Wthi = (unsigned short*)w; w += 6 * 16384 * sizeof(unsigned short);
  unsigned short* Wtlo = (unsigned short*)w; w += 6 * 16384 * sizeof(unsigned short);
  float* scv = (float*)w; w += NL * 2 * DD * sizeof(float);
  float* shv = (float*)w; w += NL * 2 * DD * sizeof(float);
  int* counts = (int*)w;  w += 200192;
  int* offs   = (int*)w;  w += 200192;
  int* cursor = (int*)w;  w += 200192;
  int* bsum   = (int*)w;  w += 1024;
  int* csr_src= (int*)w;  w += (size_t)NE * sizeof(int);

  const int NBLK = (NN + 255) / 256;   // 196

  // CSR build (4-way ILP on the atomic chains)
  hipMemsetAsync(counts, 0, (size_t)NN * sizeof(int), stream);
  k_count<<<(E4 + 255) / 256, 256, 0, stream>>>(dst, counts);
  k_scan1<<<NBLK, 256, 0, stream>>>(counts, offs, bsum);
  k_scan2<<<1, 256, 0, stream>>>(bsum, NBLK);
  k_scan3<<<NBLK, 256, 0, stream>>>(offs, bsum, cursor);
  k_fill<<<(E4 + 255) / 256, 256, 0, stream>>>(src, dst, cursor, csr_src);

  // weight / BN prep + x split
  k_prep_w<<<384, 256, 0, stream>>>(W1, W2, Wthi, Wtlo);
  k_prep_bn<<<3, 256, 0, stream>>>(b1, b2, g, be, rm, rv, scv, shv);
  k_cvt<<<NN * DD / 8 / 256, 256, 0, stream>>>(x, Shi, Slo);

  const int AGG_BLOCKS  = NN * 16 / 256;        // 3125
  const int GEMM_BLOCKS = (NN + 63) / 64;       // 782

  for (int i = 0; i < NL; ++i){
    k_agg<<<AGG_BLOCKS, 256, 0, stream>>>(Shi, Slo, offs, counts, csr_src, Ahi, Alo);

    const unsigned short* W1t_hi = Wthi + (size_t)(i * 2 + 0) * 16384;
    const unsigned short* W1t_lo = Wtlo + (size_t)(i * 2 + 0) * 16384;
    const unsigned short* W2t_hi = Wthi + (size_t)(i * 2 + 1) * 16384;
    const unsigned short* W2t_lo = Wtlo + (size_t)(i * 2 + 1) * 16384;
    const float* sc1 = scv + (size_t)(i * 2 + 0) * DD;
    const float* sh1 = shv + (size_t)(i * 2 + 0) * DD;
    const float* sc2 = scv + (size_t)(i * 2 + 1) * DD;
    const float* sh2 = shv + (size_t)(i * 2 + 1) * DD;

    k_gemm<0><<<GEMM_BLOCKS, 256, 0, stream>>>(Ahi, Alo, W1t_hi, W1t_lo,
        sc1, sh1, Hhi, Hlo, (float*)nullptr);

    if (i == NL - 1){
      k_gemm<1><<<GEMM_BLOCKS, 256, 0, stream>>>(Hhi, Hlo, W2t_hi, W2t_lo,
          sc2, sh2, (unsigned short*)nullptr, (unsigned short*)nullptr, (float*)d_out);
    } else {
      k_gemm<0><<<GEMM_BLOCKS, 256, 0, stream>>>(Hhi, Hlo, W2t_hi, W2t_lo,
          sc2, sh2, Shi, Slo, (float*)nullptr);
    }
  }
}

// Round 6
// 396.299 us; speedup vs baseline: 1.2960x; 1.1568x over previous
//
#include <hip/hip_runtime.h>
#include <stdint.h>

#define NN 50000
#define NE 800000
#define DD 128
#define NL 3
#define NB_E 200     // edge blocks for hist/bin
#define EPB 4000     // edges per block (NB_E*EPB == NE)
#define NBK 196      // dst buckets = ceil(NN/256), bucket = dst>>8
#define MH (NBK*NB_E)// blkhist elements = 39200

typedef __attribute__((ext_vector_type(8))) short short8;
typedef __attribute__((ext_vector_type(4))) float f32x4;

// ---------- bf16 helpers ----------
__device__ __forceinline__ float b2f(unsigned short u){
  union { unsigned int i; float f; } v; v.i = ((unsigned int)u) << 16; return v.f;
}
__device__ __forceinline__ unsigned short f2b(float f){
  union { float f; unsigned int i; } v; v.f = f;
  unsigned int r = 0x7FFFu + ((v.i >> 16) & 1u);
  return (unsigned short)((v.i + r) >> 16);
}

// ---------- CSR build: deterministic two-level binning ----------
// A1: per-edge-block histogram over NBK buckets
__global__ __launch_bounds__(256) void k_hist(const int* __restrict__ dst,
                                              int* __restrict__ blkhist){
  __shared__ int h[NBK];
  int t = threadIdx.x, b = blockIdx.x;
  for (int i = t; i < NBK; i += 256) h[i] = 0;
  __syncthreads();
  int e0 = b * EPB;
  for (int i = t; i < EPB; i += 256){
    int d = dst[e0 + i];
    atomicAdd(&h[d >> 8], 1);
  }
  __syncthreads();
  for (int i = t; i < NBK; i += 256) blkhist[i * NB_E + b] = h[i];  // [bucket][block]
}

// A2: generic 3-kernel exclusive scan over n elements
__global__ void k_scanA(const int* __restrict__ in, int* __restrict__ out,
                        int* __restrict__ bsum, int n){
  __shared__ int s[256];
  int t = threadIdx.x, i = blockIdx.x * 256 + t;
  int v = (i < n) ? in[i] : 0;
  s[t] = v; __syncthreads();
  for (int d = 1; d < 256; d <<= 1){
    int x = (t >= d) ? s[t - d] : 0;
    __syncthreads();
    s[t] += x;
    __syncthreads();
  }
  if (i < n) out[i] = s[t] - v;
  if (t == 255) bsum[blockIdx.x] = s[255];
}

__global__ void k_scanB(int* __restrict__ bsum, int nblk){
  __shared__ int s[256];
  int t = threadIdx.x;
  int v = (t < nblk) ? bsum[t] : 0;
  s[t] = v; __syncthreads();
  for (int d = 1; d < 256; d <<= 1){
    int x = (t >= d) ? s[t - d] : 0;
    __syncthreads();
    s[t] += x;
    __syncthreads();
  }
  if (t < nblk) bsum[t] = s[t] - v;
}

__global__ void k_scanC(int* __restrict__ out, const int* __restrict__ bsum, int n){
  int i = blockIdx.x * 256 + threadIdx.x;
  if (i < n) out[i] += bsum[blockIdx.x];
}

// A3: scatter edges into bucket-grouped array; each block's run per bucket is
// contiguous -> near-sequential stores, no cross-XCD line sharing (except run seams).
__global__ __launch_bounds__(256) void k_bin(const int* __restrict__ src,
    const int* __restrict__ dst, const int* __restrict__ pos,
    unsigned int* __restrict__ binned){
  __shared__ int cur[NBK];
  int t = threadIdx.x, b = blockIdx.x;
  for (int i = t; i < NBK; i += 256) cur[i] = pos[i * NB_E + b];
  __syncthreads();
  int e0 = b * EPB;
  for (int i = t; i < EPB; i += 256){
    int d = dst[e0 + i];
    int s = src[e0 + i];
    int p = atomicAdd(&cur[d >> 8], 1);
    binned[p] = ((unsigned int)d << 16) | (unsigned int)s;
  }
}

// A4: one block per bucket; exclusive owner of its CSR region.
// Produces offs/counts (dst-level) AND csr_src.
__global__ __launch_bounds__(256) void k_csr(const unsigned int* __restrict__ binned,
    const int* __restrict__ pos, int* __restrict__ offs, int* __restrict__ counts,
    int* __restrict__ csr_src){
  __shared__ int h[256], ex[256], cur[256];
  int t = threadIdx.x, b = blockIdx.x;
  int r0 = pos[b * NB_E];
  int r1 = (b == NBK - 1) ? NE : pos[(b + 1) * NB_E];
  h[t] = 0; __syncthreads();
  for (int i = r0 + t; i < r1; i += 256){
    unsigned int pv = binned[i];
    atomicAdd(&h[(pv >> 16) & 255], 1);
  }
  __syncthreads();
  int v = h[t];
  ex[t] = v; __syncthreads();
  for (int d = 1; d < 256; d <<= 1){
    int x = (t >= d) ? ex[t - d] : 0;
    __syncthreads();
    ex[t] += x;
    __syncthreads();
  }
  int base = r0 + ex[t] - v;        // exclusive
  cur[t] = base;
  int gd = b * 256 + t;
  if (gd < NN){ offs[gd] = base; counts[gd] = v; }
  __syncthreads();
  for (int i = r0 + t; i < r1; i += 256){
    unsigned int pv = binned[i];
    int dl = (pv >> 16) & 255;
    int s = pv & 0xFFFF;
    int p = atomicAdd(&cur[dl], 1);
    csr_src[p] = s;
  }
}

// ---------- prep: W -> transposed hi/lo bf16 split ----------
__global__ void k_prep_w(const float* __restrict__ W1, const float* __restrict__ W2,
    unsigned short* __restrict__ Wthi, unsigned short* __restrict__ Wtlo){
  int idx = blockIdx.x * 256 + threadIdx.x;   // 98304 = 6*128*128
  int mat = idx >> 14;
  int rem = idx & 16383;
  int k = rem >> 7, j = rem & 127;
  int layer = mat >> 1, which = mat & 1;
  const float* srcW = which ? W2 : W1;
  float w = srcW[layer * 16384 + k * DD + j];
  unsigned short hi = f2b(w);
  Wthi[mat * 16384 + j * DD + k] = hi;
  Wtlo[mat * 16384 + j * DD + k] = f2b(w - b2f(hi));
}

// ---------- prep: fold bias+BN into per-col scale/shift ----------
__global__ void k_prep_bn(const float* __restrict__ b1, const float* __restrict__ b2,
    const float* __restrict__ g, const float* __restrict__ be,
    const float* __restrict__ rm, const float* __restrict__ rv,
    float* __restrict__ sc, float* __restrict__ sh){
  int idx = blockIdx.x * 256 + threadIdx.x;   // 768 = 3*2*128
  if (idx >= NL * 2 * DD) return;
  int j = idx & 127;
  int w = (idx >> 7) & 1;
  int l = idx >> 8;
  int p = (l * 2 + w) * DD + j;
  float s = g[p] * rsqrtf(rv[p] + 1e-5f);
  float bias = w ? b2[l * DD + j] : b1[l * DD + j];
  sc[p] = s;
  sh[p] = fmaf(bias - rm[p], s, be[p]);
}

// ---------- x fp32 -> hi/lo bf16 split ----------
__global__ void k_cvt(const float* __restrict__ x,
    unsigned short* __restrict__ hi, unsigned short* __restrict__ lo){
  int i = blockIdx.x * 256 + threadIdx.x;     // 8-elem units; grid covers NN*DD/8
  float4 a = ((const float4*)x)[2 * i];
  float4 b = ((const float4*)x)[2 * i + 1];
  float v[8] = {a.x, a.y, a.z, a.w, b.x, b.y, b.z, b.w};
  short8 h8, l8;
  #pragma unroll
  for (int c = 0; c < 8; ++c){
    unsigned short h = f2b(v[c]);
    h8[c] = (short)h; l8[c] = (short)f2b(v[c] - b2f(h));
  }
  ((short8*)hi)[i] = h8;
  ((short8*)lo)[i] = l8;
}

// ---------- aggregate: A = (Shi+Slo)[v] + sum_nbr Shi[src] ; write hi/lo split ----------
__global__ __launch_bounds__(256) void k_agg(
    const unsigned short* __restrict__ Shi, const unsigned short* __restrict__ Slo,
    const int* __restrict__ offs, const int* __restrict__ counts,
    const int* __restrict__ csr_src,
    unsigned short* __restrict__ Ahi, unsigned short* __restrict__ Alo){
  int t = blockIdx.x * 256 + threadIdx.x;
  int row = t >> 4;                // 16 rows / block; grid 3125 covers exactly NN
  int l = t & 15;
  const short8* H = (const short8*)Shi;   // 16 x short8 per row
  const short8* L = (const short8*)Slo;
  int idx = row * 16 + l;
  short8 s_h = H[idx]; short8 s_l = L[idx];
  float acc[8];
  #pragma unroll
  for (int i = 0; i < 8; ++i)
    acc[i] = b2f((unsigned short)s_h[i]) + b2f((unsigned short)s_l[i]);

  int e = offs[row];
  int end = e + counts[row];
  for (; e + 4 <= end; e += 4){
    int s0 = csr_src[e], s1 = csr_src[e+1], s2 = csr_src[e+2], s3 = csr_src[e+3];
    short8 g0 = H[s0*16 + l], g1 = H[s1*16 + l], g2 = H[s2*16 + l], g3 = H[s3*16 + l];
    #pragma unroll
    for (int i = 0; i < 8; ++i){
      acc[i] += b2f((unsigned short)g0[i]) + b2f((unsigned short)g1[i])
              + b2f((unsigned short)g2[i]) + b2f((unsigned short)g3[i]);
    }
  }
  for (; e < end; ++e){
    short8 g0 = H[csr_src[e]*16 + l];
    #pragma unroll
    for (int i = 0; i < 8; ++i) acc[i] += b2f((unsigned short)g0[i]);
  }

  short8 oh, ol;
  #pragma unroll
  for (int i = 0; i < 8; ++i){
    unsigned short h = f2b(acc[i]);
    oh[i] = (short)h; ol[i] = (short)f2b(acc[i] - b2f(h));
  }
  ((short8*)Ahi)[idx] = oh;
  ((short8*)Alo)[idx] = ol;
}

// ---------- LDS-free split-bf16 MFMA GEMM + BN + ReLU ----------
// Block 256 = 4 waves; wave = 32 rows x 64 cols (2 row-tiles, 2x B reuse).
// Epilogue: wave-private LDS staging -> coalesced 16B stores (no barriers).
#define SSTR 72   // LDS tile row stride (ushort or float units)
template<int LAST>
__global__ __launch_bounds__(256) void k_gemm(
    const unsigned short* __restrict__ Ahi, const unsigned short* __restrict__ Alo,
    const unsigned short* __restrict__ Wthi, const unsigned short* __restrict__ Wtlo,
    const float* __restrict__ sc, const float* __restrict__ sh,
    unsigned short* __restrict__ Ohi, unsigned short* __restrict__ Olo,
    float* __restrict__ Of)
{
  __shared__ __align__(16) char smem[4][32 * SSTR * 4];   // 36864 B: per-wave 9216 B
  int t = threadIdx.x;
  int wave = t >> 6, lane = t & 63, l16 = lane & 15, q = lane >> 4;
  int rowbase = blockIdx.x * 64 + (wave >> 1) * 32;
  int colbase = (wave & 1) * 64;

  int ar0 = rowbase + l16;      if (ar0 > NN - 1) ar0 = NN - 1;
  int ar1 = rowbase + 16 + l16; if (ar1 > NN - 1) ar1 = NN - 1;

  const short8* AH = (const short8*)Ahi;   // [row][16]
  const short8* AL = (const short8*)Alo;
  const short8* BH = (const short8*)Wthi;  // [j][16]
  const short8* BL = (const short8*)Wtlo;

  f32x4 acc[2][4];
  #pragma unroll
  for (int rt = 0; rt < 2; ++rt)
    #pragma unroll
    for (int ct = 0; ct < 4; ++ct) acc[rt][ct] = (f32x4){0.f, 0.f, 0.f, 0.f};

  #pragma unroll
  for (int kc = 0; kc < 4; ++kc){
    short8 ah0 = AH[ar0 * 16 + kc * 4 + q];
    short8 al0 = AL[ar0 * 16 + kc * 4 + q];
    short8 ah1 = AH[ar1 * 16 + kc * 4 + q];
    short8 al1 = AL[ar1 * 16 + kc * 4 + q];
    #pragma unroll
    for (int ct = 0; ct < 4; ++ct){
      int wr = colbase + ct * 16 + l16;
      short8 bh = BH[wr * 16 + kc * 4 + q];
      short8 bl = BL[wr * 16 + kc * 4 + q];
      acc[0][ct] = __builtin_amdgcn_mfma_f32_16x16x32_bf16(ah0, bh, acc[0][ct], 0, 0, 0);
      acc[0][ct] = __builtin_amdgcn_mfma_f32_16x16x32_bf16(ah0, bl, acc[0][ct], 0, 0, 0);
      acc[0][ct] = __builtin_amdgcn_mfma_f32_16x16x32_bf16(al0, bh, acc[0][ct], 0, 0, 0);
      acc[1][ct] = __builtin_amdgcn_mfma_f32_16x16x32_bf16(ah1, bh, acc[1][ct], 0, 0, 0);
      acc[1][ct] = __builtin_amdgcn_mfma_f32_16x16x32_bf16(ah1, bl, acc[1][ct], 0, 0, 0);
      acc[1][ct] = __builtin_amdgcn_mfma_f32_16x16x32_bf16(al1, bh, acc[1][ct], 0, 0, 0);
    }
  }

  if (!LAST){
    unsigned short* shh = (unsigned short*)smem[wave];      // 32 x SSTR hi
    unsigned short* shl = shh + 32 * SSTR;                  // 32 x SSTR lo
    #pragma unroll
    for (int rt = 0; rt < 2; ++rt)
      #pragma unroll
      for (int ct = 0; ct < 4; ++ct){
        int colg = colbase + ct * 16 + l16;
        float s = sc[colg], b = sh[colg];
        #pragma unroll
        for (int r = 0; r < 4; ++r){
          int row_l = rt * 16 + q * 4 + r;                  // C/D layout
          float v = fmaxf(fmaf(acc[rt][ct][r], s, b), 0.f);
          unsigned short h = f2b(v);
          shh[row_l * SSTR + ct * 16 + l16] = h;
          shl[row_l * SSTR + ct * 16 + l16] = f2b(v - b2f(h));
        }
      }
    int rr = lane >> 3, cu = (lane & 7) * 8;
    #pragma unroll
    for (int i = 0; i < 4; ++i){
      int row_l = i * 8 + rr;
      int row_g = rowbase + row_l;
      short8 vh = *(const short8*)&shh[row_l * SSTR + cu];
      short8 vl = *(const short8*)&shl[row_l * SSTR + cu];
      if (row_g < NN){
        *(short8*)&Ohi[row_g * DD + colbase + cu] = vh;
        *(short8*)&Olo[row_g * DD + colbase + cu] = vl;
      }
    }
  } else {
    float* sf = (float*)smem[wave];                         // 32 x SSTR fp32
    #pragma unroll
    for (int rt = 0; rt < 2; ++rt)
      #pragma unroll
      for (int ct = 0; ct < 4; ++ct){
        int colg = colbase + ct * 16 + l16;
        float s = sc[colg], b = sh[colg];
        #pragma unroll
        for (int r = 0; r < 4; ++r){
          int row_l = rt * 16 + q * 4 + r;
          sf[row_l * SSTR + ct * 16 + l16] = fmaxf(fmaf(acc[rt][ct][r], s, b), 0.f);
        }
      }
    int rr = lane >> 4, cf = (lane & 15) * 4;
    #pragma unroll
    for (int i = 0; i < 8; ++i){
      int row_l = i * 4 + rr;
      int row_g = rowbase + row_l;
      float4 v = *(const float4*)&sf[row_l * SSTR + cf];
      if (row_g < NN) *(float4*)&Of[row_g * DD + colbase + cf] = v;
    }
  }
}

// ---------- launch ----------
extern "C" void kernel_launch(void* const* d_in, const int* in_sizes, int n_in,
                              void* d_out, int out_size, void* d_ws, size_t ws_size,
                              hipStream_t stream) {
  const float* x  = (const float*)d_in[0];
  const int* ei   = (const int*)d_in[1];
  const float* W1 = (const float*)d_in[2];
  const float* b1 = (const float*)d_in[3];
  const float* W2 = (const float*)d_in[4];
  const float* b2 = (const float*)d_in[5];
  const float* g  = (const float*)d_in[6];
  const float* be = (const float*)d_in[7];
  const float* rm = (const float*)d_in[8];
  const float* rv = (const float*)d_in[9];

  const int* src = ei;
  const int* dst = ei + NE;

  char* w = (char*)d_ws;
  const size_t HB = (size_t)NN * DD * sizeof(unsigned short);  // 12.8 MB
  unsigned short* Shi = (unsigned short*)w; w += HB;  // h table hi
  unsigned short* Slo = (unsigned short*)w; w += HB;  // h table lo
  unsigned short* Ahi = (unsigned short*)w; w += HB;  // agg out hi
  unsigned short* Alo = (unsigned short*)w; w += HB;
  unsigned short* Hhi = (unsigned short*)w; w += HB;  // gemm1 out hi
  unsigned short* Hlo = (unsigned short*)w; w += HB;
  unsigned short* Wthi = (unsigned short*)w; w += 6 * 16384 * sizeof(unsigned short);
  unsigned short* Wtlo = (unsigned short*)w; w += 6 * 16384 * sizeof(unsigned short);
  float* scv = (float*)w; w += NL * 2 * DD * sizeof(float);
  float* shv = (float*)w; w += NL * 2 * DD * sizeof(float);
  int* counts  = (int*)w; w += 200192;
  int* offs    = (int*)w; w += 200192;
  int* blkhist = (int*)w; w += MH * sizeof(int);
  int* pos     = (int*)w; w += MH * sizeof(int);
  int* bsum    = (int*)w; w += 1024;
  unsigned int* binned = (unsigned int*)w; w += (size_t)NE * sizeof(unsigned int);
  int* csr_src = (int*)w; w += (size_t)NE * sizeof(int);

  // CSR build: deterministic two-level binning (no cross-XCD line sharing)
  const int SCAN_BLK = (MH + 255) / 256;   // 154
  k_hist<<<NB_E, 256, 0, stream>>>(dst, blkhist);
  k_scanA<<<SCAN_BLK, 256, 0, stream>>>(blkhist, pos, bsum, MH);
  k_scanB<<<1, 256, 0, stream>>>(bsum, SCAN_BLK);
  k_scanC<<<SCAN_BLK, 256, 0, stream>>>(pos, bsum, MH);
  k_bin<<<NB_E, 256, 0, stream>>>(src, dst, pos, binned);
  k_csr<<<NBK, 256, 0, stream>>>(binned, pos, offs, counts, csr_src);

  // weight / BN prep + x split
  k_prep_w<<<384, 256, 0, stream>>>(W1, W2, Wthi, Wtlo);
  k_prep_bn<<<3, 256, 0, stream>>>(b1, b2, g, be, rm, rv, scv, shv);
  k_cvt<<<NN * DD / 8 / 256, 256, 0, stream>>>(x, Shi, Slo);

  const int AGG_BLOCKS  = NN * 16 / 256;        // 3125
  const int GEMM_BLOCKS = (NN + 63) / 64;       // 782

  for (int i = 0; i < NL; ++i){
    k_agg<<<AGG_BLOCKS, 256, 0, stream>>>(Shi, Slo, offs, counts, csr_src, Ahi, Alo);

    const unsigned short* W1t_hi = Wthi + (size_t)(i * 2 + 0) * 16384;
    const unsigned short* W1t_lo = Wtlo + (size_t)(i * 2 + 0) * 16384;
    const unsigned short* W2t_hi = Wthi + (size_t)(i * 2 + 1) * 16384;
    const unsigned short* W2t_lo = Wtlo + (size_t)(i * 2 + 1) * 16384;
    const float* sc1 = scv + (size_t)(i * 2 + 0) * DD;
    const float* sh1 = shv + (size_t)(i * 2 + 0) * DD;
    const float* sc2 = scv + (size_t)(i * 2 + 1) * DD;
    const float* sh2 = shv + (size_t)(i * 2 + 1) * DD;

    k_gemm<0><<<GEMM_BLOCKS, 256, 0, stream>>>(Ahi, Alo, W1t_hi, W1t_lo,
        sc1, sh1, Hhi, Hlo, (float*)nullptr);

    if (i == NL - 1){
      k_gemm<1><<<GEMM_BLOCKS, 256, 0, stream>>>(Hhi, Hlo, W2t_hi, W2t_lo,
          sc2, sh2, (unsigned short*)nullptr, (unsigned short*)nullptr, (float*)d_out);
    } else {
      k_gemm<0><<<GEMM_BLOCKS, 256, 0, stream>>>(Hhi, Hlo, W2t_hi, W2t_lo,
          sc2, sh2, Shi, Slo, (float*)nullptr);
    }
  }
}

// Round 7
// 394.908 us; speedup vs baseline: 1.3005x; 1.0035x over previous
//
#include <hip/hip_runtime.h>
#include <stdint.h>

#define NN 50000
#define NE 800000
#define DD 128
#define NL 3
#define NB_E 200     // edge blocks for hist/bin
#define EPB 4000     // edges per block (NB_E*EPB == NE)
#define NBK 196      // dst buckets = ceil(NN/256), bucket = dst>>8
#define MH (NBK*NB_E)// blkhist elements = 39200
#define LSTR 136     // LDS ushort stride per row (272 B, 16B-aligned)

typedef __attribute__((ext_vector_type(8))) short short8;
typedef __attribute__((ext_vector_type(4))) float f32x4;

// ---------- bf16 helpers ----------
__device__ __forceinline__ float b2f(unsigned short u){
  union { unsigned int i; float f; } v; v.i = ((unsigned int)u) << 16; return v.f;
}
__device__ __forceinline__ unsigned short f2b(float f){
  union { float f; unsigned int i; } v; v.f = f;
  unsigned int r = 0x7FFFu + ((v.i >> 16) & 1u);
  return (unsigned short)((v.i + r) >> 16);
}

// ---------- CSR build: deterministic two-level binning ----------
__global__ __launch_bounds__(256) void k_hist(const int* __restrict__ dst,
                                              int* __restrict__ blkhist){
  __shared__ int h[NBK];
  int t = threadIdx.x, b = blockIdx.x;
  for (int i = t; i < NBK; i += 256) h[i] = 0;
  __syncthreads();
  int e0 = b * EPB;
  for (int i = t; i < EPB; i += 256){
    int d = dst[e0 + i];
    atomicAdd(&h[d >> 8], 1);
  }
  __syncthreads();
  for (int i = t; i < NBK; i += 256) blkhist[i * NB_E + b] = h[i];
}

__global__ void k_scanA(const int* __restrict__ in, int* __restrict__ out,
                        int* __restrict__ bsum, int n){
  __shared__ int s[256];
  int t = threadIdx.x, i = blockIdx.x * 256 + t;
  int v = (i < n) ? in[i] : 0;
  s[t] = v; __syncthreads();
  for (int d = 1; d < 256; d <<= 1){
    int x = (t >= d) ? s[t - d] : 0;
    __syncthreads();
    s[t] += x;
    __syncthreads();
  }
  if (i < n) out[i] = s[t] - v;
  if (t == 255) bsum[blockIdx.x] = s[255];
}

__global__ void k_scanB(int* __restrict__ bsum, int nblk){
  __shared__ int s[256];
  int t = threadIdx.x;
  int v = (t < nblk) ? bsum[t] : 0;
  s[t] = v; __syncthreads();
  for (int d = 1; d < 256; d <<= 1){
    int x = (t >= d) ? s[t - d] : 0;
    __syncthreads();
    s[t] += x;
    __syncthreads();
  }
  if (t < nblk) bsum[t] = s[t] - v;
}

__global__ void k_scanC(int* __restrict__ out, const int* __restrict__ bsum, int n){
  int i = blockIdx.x * 256 + threadIdx.x;
  if (i < n) out[i] += bsum[blockIdx.x];
}

__global__ __launch_bounds__(256) void k_bin(const int* __restrict__ src,
    const int* __restrict__ dst, const int* __restrict__ pos,
    unsigned int* __restrict__ binned){
  __shared__ int cur[NBK];
  int t = threadIdx.x, b = blockIdx.x;
  for (int i = t; i < NBK; i += 256) cur[i] = pos[i * NB_E + b];
  __syncthreads();
  int e0 = b * EPB;
  for (int i = t; i < EPB; i += 256){
    int d = dst[e0 + i];
    int s = src[e0 + i];
    int p = atomicAdd(&cur[d >> 8], 1);
    binned[p] = ((unsigned int)d << 16) | (unsigned int)s;
  }
}

__global__ __launch_bounds__(256) void k_csr(const unsigned int* __restrict__ binned,
    const int* __restrict__ pos, int* __restrict__ offs, int* __restrict__ counts,
    int* __restrict__ csr_src){
  __shared__ int h[256], ex[256], cur[256];
  int t = threadIdx.x, b = blockIdx.x;
  int r0 = pos[b * NB_E];
  int r1 = (b == NBK - 1) ? NE : pos[(b + 1) * NB_E];
  h[t] = 0; __syncthreads();
  for (int i = r0 + t; i < r1; i += 256){
    unsigned int pv = binned[i];
    atomicAdd(&h[(pv >> 16) & 255], 1);
  }
  __syncthreads();
  int v = h[t];
  ex[t] = v; __syncthreads();
  for (int d = 1; d < 256; d <<= 1){
    int x = (t >= d) ? ex[t - d] : 0;
    __syncthreads();
    ex[t] += x;
    __syncthreads();
  }
  int base = r0 + ex[t] - v;
  cur[t] = base;
  int gd = b * 256 + t;
  if (gd < NN){ offs[gd] = base; counts[gd] = v; }
  __syncthreads();
  for (int i = r0 + t; i < r1; i += 256){
    unsigned int pv = binned[i];
    int dl = (pv >> 16) & 255;
    int s = pv & 0xFFFF;
    int p = atomicAdd(&cur[dl], 1);
    csr_src[p] = s;
  }
}

// ---------- prep: W -> transposed hi/lo bf16 split ----------
__global__ void k_prep_w(const float* __restrict__ W1, const float* __restrict__ W2,
    unsigned short* __restrict__ Wthi, unsigned short* __restrict__ Wtlo){
  int idx = blockIdx.x * 256 + threadIdx.x;   // 98304 = 6*128*128
  int mat = idx >> 14;
  int rem = idx & 16383;
  int k = rem >> 7, j = rem & 127;
  int layer = mat >> 1, which = mat & 1;
  const float* srcW = which ? W2 : W1;
  float w = srcW[layer * 16384 + k * DD + j];
  unsigned short hi = f2b(w);
  Wthi[mat * 16384 + j * DD + k] = hi;
  Wtlo[mat * 16384 + j * DD + k] = f2b(w - b2f(hi));
}

// ---------- prep: fold bias+BN into per-col scale/shift ----------
__global__ void k_prep_bn(const float* __restrict__ b1, const float* __restrict__ b2,
    const float* __restrict__ g, const float* __restrict__ be,
    const float* __restrict__ rm, const float* __restrict__ rv,
    float* __restrict__ sc, float* __restrict__ sh){
  int idx = blockIdx.x * 256 + threadIdx.x;   // 768 = 3*2*128
  if (idx >= NL * 2 * DD) return;
  int j = idx & 127;
  int w = (idx >> 7) & 1;
  int l = idx >> 8;
  int p = (l * 2 + w) * DD + j;
  float s = g[p] * rsqrtf(rv[p] + 1e-5f);
  float bias = w ? b2[l * DD + j] : b1[l * DD + j];
  sc[p] = s;
  sh[p] = fmaf(bias - rm[p], s, be[p]);
}

// ---------- x fp32 -> hi/lo bf16 split ----------
__global__ void k_cvt(const float* __restrict__ x,
    unsigned short* __restrict__ hi, unsigned short* __restrict__ lo){
  int i = blockIdx.x * 256 + threadIdx.x;     // 8-elem units
  float4 a = ((const float4*)x)[2 * i];
  float4 b = ((const float4*)x)[2 * i + 1];
  float v[8] = {a.x, a.y, a.z, a.w, b.x, b.y, b.z, b.w};
  short8 h8, l8;
  #pragma unroll
  for (int c = 0; c < 8; ++c){
    unsigned short h = f2b(v[c]);
    h8[c] = (short)h; l8[c] = (short)f2b(v[c] - b2f(h));
  }
  ((short8*)hi)[i] = h8;
  ((short8*)lo)[i] = l8;
}

// ---------- fused layer: agg -> gemm1 -> BN/ReLU -> gemm2 -> BN/ReLU ----------
// Block: 256 thr = 4 waves, 32 rows x 128 cols. LDS 34,816 B:
//   A hi [0..8704) A lo [8704..17408) H hi [17408..26112) H lo [26112..34816)
// Phase1: 8 lanes/row gather-aggregate into A (hi/lo split).
// Phase2/3: MFMA split-bf16; W fragments from global (L2-hot, 64KB/mat).
template<int LAST>
__global__ __launch_bounds__(256) void k_layer(
    const unsigned short* __restrict__ Shi, const unsigned short* __restrict__ Slo,
    const int* __restrict__ offs, const int* __restrict__ counts,
    const int* __restrict__ csr_src,
    const unsigned short* __restrict__ W1h, const unsigned short* __restrict__ W1l,
    const unsigned short* __restrict__ W2h, const unsigned short* __restrict__ W2l,
    const float* __restrict__ sc1, const float* __restrict__ sh1,
    const float* __restrict__ sc2, const float* __restrict__ sh2,
    unsigned short* __restrict__ Ohi, unsigned short* __restrict__ Olo,
    float* __restrict__ Of)
{
  __shared__ __align__(16) char smem[4 * 32 * LSTR * 2];   // 34,816 B
  unsigned short* Ahi_s = (unsigned short*)smem;
  unsigned short* Alo_s = Ahi_s + 32 * LSTR;
  unsigned short* Hhi_s = Alo_s + 32 * LSTR;
  unsigned short* Hlo_s = Hhi_s + 32 * LSTR;

  int t = threadIdx.x;
  int base = blockIdx.x * 32;

  // ---- phase 1: aggregate 32 rows (8 lanes/row, 16 cols each) ----
  {
    int row_l = t >> 3, p = t & 7;
    int row_g = base + row_l; if (row_g > NN - 1) row_g = NN - 1;
    const short8* H8 = (const short8*)Shi;   // [row][16]
    const short8* L8 = (const short8*)Slo;
    float acc[16];
    short8 sh0 = H8[row_g * 16 + p * 2], sh1v_ = H8[row_g * 16 + p * 2 + 1];
    short8 sl0 = L8[row_g * 16 + p * 2], sl1v_ = L8[row_g * 16 + p * 2 + 1];
    #pragma unroll
    for (int c = 0; c < 8; ++c){
      acc[c]     = b2f((unsigned short)sh0[c])  + b2f((unsigned short)sl0[c]);
      acc[8 + c] = b2f((unsigned short)sh1v_[c]) + b2f((unsigned short)sl1v_[c]);
    }
    int e = offs[row_g];
    int end = e + counts[row_g];
    for (; e + 2 <= end; e += 2){
      int s0 = csr_src[e], s1 = csr_src[e + 1];
      short8 a0 = H8[s0 * 16 + p * 2], a1 = H8[s0 * 16 + p * 2 + 1];
      short8 b0 = H8[s1 * 16 + p * 2], b1 = H8[s1 * 16 + p * 2 + 1];
      #pragma unroll
      for (int c = 0; c < 8; ++c){
        acc[c]     += b2f((unsigned short)a0[c]) + b2f((unsigned short)b0[c]);
        acc[8 + c] += b2f((unsigned short)a1[c]) + b2f((unsigned short)b1[c]);
      }
    }
    if (e < end){
      int s0 = csr_src[e];
      short8 a0 = H8[s0 * 16 + p * 2], a1 = H8[s0 * 16 + p * 2 + 1];
      #pragma unroll
      for (int c = 0; c < 8; ++c){
        acc[c]     += b2f((unsigned short)a0[c]);
        acc[8 + c] += b2f((unsigned short)a1[c]);
      }
    }
    short8 oh0, ol0, oh1, ol1;
    #pragma unroll
    for (int c = 0; c < 8; ++c){
      unsigned short h0 = f2b(acc[c]);
      oh0[c] = (short)h0; ol0[c] = (short)f2b(acc[c] - b2f(h0));
      unsigned short h1 = f2b(acc[8 + c]);
      oh1[c] = (short)h1; ol1[c] = (short)f2b(acc[8 + c] - b2f(h1));
    }
    *(short8*)&Ahi_s[row_l * LSTR + p * 16]     = oh0;
    *(short8*)&Ahi_s[row_l * LSTR + p * 16 + 8] = oh1;
    *(short8*)&Alo_s[row_l * LSTR + p * 16]     = ol0;
    *(short8*)&Alo_s[row_l * LSTR + p * 16 + 8] = ol1;
  }
  __syncthreads();

  // ---- phase 2: gemm1 ----
  int wave = t >> 6, lane = t & 63, l16 = lane & 15, q = lane >> 4;
  int r0 = (wave >> 1) * 16;     // block-local tile rows
  int c0 = (wave & 1) * 64;      // tile cols
  const short8* B1H = (const short8*)W1h;   // [j][16]
  const short8* B1L = (const short8*)W1l;
  const short8* B2H = (const short8*)W2h;
  const short8* B2L = (const short8*)W2l;

  f32x4 acc[4];
  #pragma unroll
  for (int ct = 0; ct < 4; ++ct) acc[ct] = (f32x4){0.f, 0.f, 0.f, 0.f};
  #pragma unroll
  for (int kc = 0; kc < 4; ++kc){
    short8 ah = *(const short8*)&Ahi_s[(r0 + l16) * LSTR + kc * 32 + q * 8];
    short8 al = *(const short8*)&Alo_s[(r0 + l16) * LSTR + kc * 32 + q * 8];
    #pragma unroll
    for (int ct = 0; ct < 4; ++ct){
      int wr = c0 + ct * 16 + l16;
      short8 bh = B1H[wr * 16 + kc * 4 + q];
      short8 bl = B1L[wr * 16 + kc * 4 + q];
      acc[ct] = __builtin_amdgcn_mfma_f32_16x16x32_bf16(ah, bh, acc[ct], 0, 0, 0);
      acc[ct] = __builtin_amdgcn_mfma_f32_16x16x32_bf16(ah, bl, acc[ct], 0, 0, 0);
      acc[ct] = __builtin_amdgcn_mfma_f32_16x16x32_bf16(al, bh, acc[ct], 0, 0, 0);
    }
  }
  // BN1 + ReLU -> stage H (hi/lo)
  #pragma unroll
  for (int ct = 0; ct < 4; ++ct){
    int col = c0 + ct * 16 + l16;
    float s = sc1[col], b = sh1[col];
    #pragma unroll
    for (int r = 0; r < 4; ++r){
      int rl = r0 + q * 4 + r;     // C/D layout: row=(lane>>4)*4+reg
      float v = fmaxf(fmaf(acc[ct][r], s, b), 0.f);
      unsigned short h = f2b(v);
      Hhi_s[rl * LSTR + col] = h;
      Hlo_s[rl * LSTR + col] = f2b(v - b2f(h));
    }
  }
  __syncthreads();

  // ---- phase 3: gemm2 ----
  f32x4 acc2[4];
  #pragma unroll
  for (int ct = 0; ct < 4; ++ct) acc2[ct] = (f32x4){0.f, 0.f, 0.f, 0.f};
  #pragma unroll
  for (int kc = 0; kc < 4; ++kc){
    short8 ah = *(const short8*)&Hhi_s[(r0 + l16) * LSTR + kc * 32 + q * 8];
    short8 al = *(const short8*)&Hlo_s[(r0 + l16) * LSTR + kc * 32 + q * 8];
    #pragma unroll
    for (int ct = 0; ct < 4; ++ct){
      int wr = c0 + ct * 16 + l16;
      short8 bh = B2H[wr * 16 + kc * 4 + q];
      short8 bl = B2L[wr * 16 + kc * 4 + q];
      acc2[ct] = __builtin_amdgcn_mfma_f32_16x16x32_bf16(ah, bh, acc2[ct], 0, 0, 0);
      acc2[ct] = __builtin_amdgcn_mfma_f32_16x16x32_bf16(ah, bl, acc2[ct], 0, 0, 0);
      acc2[ct] = __builtin_amdgcn_mfma_f32_16x16x32_bf16(al, bh, acc2[ct], 0, 0, 0);
    }
  }

  // ---- epilogue: BN2 + ReLU; stage in A region (dead), coalesced store ----
  if (!LAST){
    #pragma unroll
    for (int ct = 0; ct < 4; ++ct){
      int col = c0 + ct * 16 + l16;
      float s = sc2[col], b = sh2[col];
      #pragma unroll
      for (int r = 0; r < 4; ++r){
        int rl = r0 + q * 4 + r;
        float v = fmaxf(fmaf(acc2[ct][r], s, b), 0.f);
        unsigned short h = f2b(v);
        Ahi_s[rl * LSTR + col] = h;
        Alo_s[rl * LSTR + col] = f2b(v - b2f(h));
      }
    }
    // wave-private readback: 16 rows x 64 cols, 2 iters x (8 rows x 8 chunks)
    int rr = lane >> 3, ch = lane & 7;
    #pragma unroll
    for (int i = 0; i < 2; ++i){
      int rl = r0 + i * 8 + rr;
      int rg = base + rl;
      short8 vh = *(const short8*)&Ahi_s[rl * LSTR + c0 + ch * 8];
      short8 vl = *(const short8*)&Alo_s[rl * LSTR + c0 + ch * 8];
      if (rg < NN){
        *(short8*)&Ohi[rg * DD + c0 + ch * 8] = vh;
        *(short8*)&Olo[rg * DD + c0 + ch * 8] = vl;
      }
    }
  } else {
    float* Cf = (float*)smem;      // 32 x 132 floats = 16,896 B (fits A region)
    #pragma unroll
    for (int ct = 0; ct < 4; ++ct){
      int col = c0 + ct * 16 + l16;
      float s = sc2[col], b = sh2[col];
      #pragma unroll
      for (int r = 0; r < 4; ++r){
        int rl = r0 + q * 4 + r;
        Cf[rl * 132 + col] = fmaxf(fmaf(acc2[ct][r], s, b), 0.f);
      }
    }
    int rr = lane >> 4, cf = (lane & 15) * 4;
    #pragma unroll
    for (int i = 0; i < 4; ++i){
      int rl = r0 + i * 4 + rr;
      int rg = base + rl;
      float4 v = *(const float4*)&Cf[rl * 132 + c0 + cf];
      if (rg < NN) *(float4*)&Of[rg * DD + c0 + cf] = v;
    }
  }
}

// ---------- launch ----------
extern "C" void kernel_launch(void* const* d_in, const int* in_sizes, int n_in,
                              void* d_out, int out_size, void* d_ws, size_t ws_size,
                              hipStream_t stream) {
  const float* x  = (const float*)d_in[0];
  const int* ei   = (const int*)d_in[1];
  const float* W1 = (const float*)d_in[2];
  const float* b1 = (const float*)d_in[3];
  const float* W2 = (const float*)d_in[4];
  const float* b2 = (const float*)d_in[5];
  const float* g  = (const float*)d_in[6];
  const float* be = (const float*)d_in[7];
  const float* rm = (const float*)d_in[8];
  const float* rv = (const float*)d_in[9];

  const int* src = ei;
  const int* dst = ei + NE;

  char* w = (char*)d_ws;
  const size_t HB = (size_t)NN * DD * sizeof(unsigned short);  // 12.8 MB
  unsigned short* S0hi = (unsigned short*)w; w += HB;
  unsigned short* S0lo = (unsigned short*)w; w += HB;
  unsigned short* S1hi = (unsigned short*)w; w += HB;
  unsigned short* S1lo = (unsigned short*)w; w += HB;
  unsigned short* Wthi = (unsigned short*)w; w += 6 * 16384 * sizeof(unsigned short);
  unsigned short* Wtlo = (unsigned short*)w; w += 6 * 16384 * sizeof(unsigned short);
  float* scv = (float*)w; w += NL * 2 * DD * sizeof(float);
  float* shv = (float*)w; w += NL * 2 * DD * sizeof(float);
  int* counts  = (int*)w; w += 200192;
  int* offs    = (int*)w; w += 200192;
  int* blkhist = (int*)w; w += MH * sizeof(int);
  int* pos     = (int*)w; w += MH * sizeof(int);
  int* bsum    = (int*)w; w += 1024;
  unsigned int* binned = (unsigned int*)w; w += (size_t)NE * sizeof(unsigned int);
  int* csr_src = (int*)w; w += (size_t)NE * sizeof(int);

  // CSR build: deterministic two-level binning (no cross-XCD line sharing)
  const int SCAN_BLK = (MH + 255) / 256;   // 154
  k_hist<<<NB_E, 256, 0, stream>>>(dst, blkhist);
  k_scanA<<<SCAN_BLK, 256, 0, stream>>>(blkhist, pos, bsum, MH);
  k_scanB<<<1, 256, 0, stream>>>(bsum, SCAN_BLK);
  k_scanC<<<SCAN_BLK, 256, 0, stream>>>(pos, bsum, MH);
  k_bin<<<NB_E, 256, 0, stream>>>(src, dst, pos, binned);
  k_csr<<<NBK, 256, 0, stream>>>(binned, pos, offs, counts, csr_src);

  // weight / BN prep + x split
  k_prep_w<<<384, 256, 0, stream>>>(W1, W2, Wthi, Wtlo);
  k_prep_bn<<<3, 256, 0, stream>>>(b1, b2, g, be, rm, rv, scv, shv);
  k_cvt<<<NN * DD / 8 / 256, 256, 0, stream>>>(x, S0hi, S0lo);

  const int LAYER_BLOCKS = (NN + 31) / 32;   // 1563

  for (int i = 0; i < NL; ++i){
    const unsigned short* W1h = Wthi + (size_t)(i * 2 + 0) * 16384;
    const unsigned short* W1l = Wtlo + (size_t)(i * 2 + 0) * 16384;
    const unsigned short* W2h = Wthi + (size_t)(i * 2 + 1) * 16384;
    const unsigned short* W2l = Wtlo + (size_t)(i * 2 + 1) * 16384;
    const float* sc1 = scv + (size_t)(i * 2 + 0) * DD;
    const float* sh1 = shv + (size_t)(i * 2 + 0) * DD;
    const float* sc2 = scv + (size_t)(i * 2 + 1) * DD;
    const float* sh2 = shv + (size_t)(i * 2 + 1) * DD;

    const unsigned short* Ih = (i & 1) ? S1hi : S0hi;
    const unsigned short* Il = (i & 1) ? S1lo : S0lo;
    unsigned short* Oh = (i & 1) ? S0hi : S1hi;
    unsigned short* Ol = (i & 1) ? S0lo : S1lo;

    if (i == NL - 1){
      k_layer<1><<<LAYER_BLOCKS, 256, 0, stream>>>(Ih, Il, offs, counts, csr_src,
          W1h, W1l, W2h, W2l, sc1, sh1, sc2, sh2,
          (unsigned short*)nullptr, (unsigned short*)nullptr, (float*)d_out);
    } else {
      k_layer<0><<<LAYER_BLOCKS, 256, 0, stream>>>(Ih, Il, offs, counts, csr_src,
          W1h, W1l, W2h, W2l, sc1, sh1, sc2, sh2, Oh, Ol, (float*)nullptr);
    }
  }
}

// Round 8
// 373.750 us; speedup vs baseline: 1.3741x; 1.0566x over previous
//
#include <hip/hip_runtime.h>
#include <stdint.h>

#define NN 50000
#define NE 800000
#define DD 128
#define NL 3
#define NB_E 200     // edge blocks for hist/bin
#define EPB 4000     // edges per block (NB_E*EPB == NE)
#define NBK 196      // dst buckets = ceil(NN/256), bucket = dst>>8
#define MH (NBK*NB_E)// blkhist elements = 39200
#define LSTR 136     // LDS ushort stride per row (272 B, 16B-aligned)

typedef __attribute__((ext_vector_type(8))) short short8;
typedef __attribute__((ext_vector_type(4))) float f32x4;

// ---------- bf16 helpers ----------
__device__ __forceinline__ float b2f(unsigned short u){
  union { unsigned int i; float f; } v; v.i = ((unsigned int)u) << 16; return v.f;
}
__device__ __forceinline__ unsigned short f2b(float f){
  union { float f; unsigned int i; } v; v.f = f;
  unsigned int r = 0x7FFFu + ((v.i >> 16) & 1u);
  return (unsigned short)((v.i + r) >> 16);
}

// ---------- CSR build: deterministic two-level binning ----------
__global__ __launch_bounds__(256) void k_hist(const int* __restrict__ dst,
                                              int* __restrict__ blkhist){
  __shared__ int h[NBK];
  int t = threadIdx.x, b = blockIdx.x;
  for (int i = t; i < NBK; i += 256) h[i] = 0;
  __syncthreads();
  int e0 = b * EPB;
  for (int i = t; i < EPB; i += 256){
    int d = dst[e0 + i];
    atomicAdd(&h[d >> 8], 1);
  }
  __syncthreads();
  for (int i = t; i < NBK; i += 256) blkhist[i * NB_E + b] = h[i];
}

__global__ void k_scanA(const int* __restrict__ in, int* __restrict__ out,
                        int* __restrict__ bsum, int n){
  __shared__ int s[256];
  int t = threadIdx.x, i = blockIdx.x * 256 + t;
  int v = (i < n) ? in[i] : 0;
  s[t] = v; __syncthreads();
  for (int d = 1; d < 256; d <<= 1){
    int x = (t >= d) ? s[t - d] : 0;
    __syncthreads();
    s[t] += x;
    __syncthreads();
  }
  if (i < n) out[i] = s[t] - v;
  if (t == 255) bsum[blockIdx.x] = s[255];
}

__global__ void k_scanB(int* __restrict__ bsum, int nblk){
  __shared__ int s[256];
  int t = threadIdx.x;
  int v = (t < nblk) ? bsum[t] : 0;
  s[t] = v; __syncthreads();
  for (int d = 1; d < 256; d <<= 1){
    int x = (t >= d) ? s[t - d] : 0;
    __syncthreads();
    s[t] += x;
    __syncthreads();
  }
  if (t < nblk) bsum[t] = s[t] - v;
}

__global__ void k_scanC(int* __restrict__ out, const int* __restrict__ bsum, int n){
  int i = blockIdx.x * 256 + threadIdx.x;
  if (i < n) out[i] += bsum[blockIdx.x];
}

__global__ __launch_bounds__(256) void k_bin(const int* __restrict__ src,
    const int* __restrict__ dst, const int* __restrict__ pos,
    unsigned int* __restrict__ binned){
  __shared__ int cur[NBK];
  int t = threadIdx.x, b = blockIdx.x;
  for (int i = t; i < NBK; i += 256) cur[i] = pos[i * NB_E + b];
  __syncthreads();
  int e0 = b * EPB;
  for (int i = t; i < EPB; i += 256){
    int d = dst[e0 + i];
    int s = src[e0 + i];
    int p = atomicAdd(&cur[d >> 8], 1);
    binned[p] = ((unsigned int)d << 16) | (unsigned int)s;
  }
}

__global__ __launch_bounds__(256) void k_csr(const unsigned int* __restrict__ binned,
    const int* __restrict__ pos, int* __restrict__ offs, int* __restrict__ counts,
    int* __restrict__ csr_src){
  __shared__ int h[256], ex[256], cur[256];
  int t = threadIdx.x, b = blockIdx.x;
  int r0 = pos[b * NB_E];
  int r1 = (b == NBK - 1) ? NE : pos[(b + 1) * NB_E];
  h[t] = 0; __syncthreads();
  for (int i = r0 + t; i < r1; i += 256){
    unsigned int pv = binned[i];
    atomicAdd(&h[(pv >> 16) & 255], 1);
  }
  __syncthreads();
  int v = h[t];
  ex[t] = v; __syncthreads();
  for (int d = 1; d < 256; d <<= 1){
    int x = (t >= d) ? ex[t - d] : 0;
    __syncthreads();
    ex[t] += x;
    __syncthreads();
  }
  int base = r0 + ex[t] - v;
  cur[t] = base;
  int gd = b * 256 + t;
  if (gd < NN){ offs[gd] = base; counts[gd] = v; }
  __syncthreads();
  for (int i = r0 + t; i < r1; i += 256){
    unsigned int pv = binned[i];
    int dl = (pv >> 16) & 255;
    int s = pv & 0xFFFF;
    int p = atomicAdd(&cur[dl], 1);
    csr_src[p] = s;
  }
}

// ---------- prep: W -> transposed hi/lo bf16 split ----------
__global__ void k_prep_w(const float* __restrict__ W1, const float* __restrict__ W2,
    unsigned short* __restrict__ Wthi, unsigned short* __restrict__ Wtlo){
  int idx = blockIdx.x * 256 + threadIdx.x;   // 98304 = 6*128*128
  int mat = idx >> 14;
  int rem = idx & 16383;
  int k = rem >> 7, j = rem & 127;
  int layer = mat >> 1, which = mat & 1;
  const float* srcW = which ? W2 : W1;
  float w = srcW[layer * 16384 + k * DD + j];
  unsigned short hi = f2b(w);
  Wthi[mat * 16384 + j * DD + k] = hi;
  Wtlo[mat * 16384 + j * DD + k] = f2b(w - b2f(hi));
}

// ---------- prep: fold bias+BN into per-col scale/shift ----------
__global__ void k_prep_bn(const float* __restrict__ b1, const float* __restrict__ b2,
    const float* __restrict__ g, const float* __restrict__ be,
    const float* __restrict__ rm, const float* __restrict__ rv,
    float* __restrict__ sc, float* __restrict__ sh){
  int idx = blockIdx.x * 256 + threadIdx.x;   // 768 = 3*2*128
  if (idx >= NL * 2 * DD) return;
  int j = idx & 127;
  int w = (idx >> 7) & 1;
  int l = idx >> 8;
  int p = (l * 2 + w) * DD + j;
  float s = g[p] * rsqrtf(rv[p] + 1e-5f);
  float bias = w ? b2[l * DD + j] : b1[l * DD + j];
  sc[p] = s;
  sh[p] = fmaf(bias - rm[p], s, be[p]);
}

// ---------- x fp32 -> hi/lo bf16 split ----------
__global__ void k_cvt(const float* __restrict__ x,
    unsigned short* __restrict__ hi, unsigned short* __restrict__ lo){
  int i = blockIdx.x * 256 + threadIdx.x;     // 8-elem units
  float4 a = ((const float4*)x)[2 * i];
  float4 b = ((const float4*)x)[2 * i + 1];
  float v[8] = {a.x, a.y, a.z, a.w, b.x, b.y, b.z, b.w};
  short8 h8, l8;
  #pragma unroll
  for (int c = 0; c < 8; ++c){
    unsigned short h = f2b(v[c]);
    h8[c] = (short)h; l8[c] = (short)f2b(v[c] - b2f(h));
  }
  ((short8*)hi)[i] = h8;
  ((short8*)lo)[i] = l8;
}

// ---------- fused layer: agg -> gemm1 -> BN/ReLU -> gemm2 -> BN/ReLU ----------
// Block: 256 thr = 4 waves, 32 rows x 128 cols. LDS 17,408 B (A region; H reuses it).
// Gather: 8 lanes/row, 4-neighbor unroll -> 8 independent 32B loads in flight.
template<int LAST>
__global__ __launch_bounds__(256, 6) void k_layer(
    const unsigned short* __restrict__ Shi, const unsigned short* __restrict__ Slo,
    const int* __restrict__ offs, const int* __restrict__ counts,
    const int* __restrict__ csr_src,
    const unsigned short* __restrict__ W1h, const unsigned short* __restrict__ W1l,
    const unsigned short* __restrict__ W2h, const unsigned short* __restrict__ W2l,
    const float* __restrict__ sc1, const float* __restrict__ sh1,
    const float* __restrict__ sc2, const float* __restrict__ sh2,
    unsigned short* __restrict__ Ohi, unsigned short* __restrict__ Olo,
    float* __restrict__ Of)
{
  __shared__ __align__(16) char smem[2 * 32 * LSTR * 2];   // 17,408 B
  unsigned short* Ahi_s = (unsigned short*)smem;            // also H-hi, also C stage
  unsigned short* Alo_s = Ahi_s + 32 * LSTR;                // also H-lo

  int t = threadIdx.x;
  int base = blockIdx.x * 32;

  // ---- phase 1: aggregate 32 rows (8 lanes/row, 4-neighbor unroll) ----
  {
    int row_l = t >> 3, p = t & 7;
    int row_g = base + row_l; if (row_g > NN - 1) row_g = NN - 1;
    const short8* H8 = (const short8*)Shi;   // [row][16]
    const short8* L8 = (const short8*)Slo;
    float acc[16];
    short8 xh0 = H8[row_g * 16 + p * 2], xh1 = H8[row_g * 16 + p * 2 + 1];
    short8 xl0 = L8[row_g * 16 + p * 2], xl1 = L8[row_g * 16 + p * 2 + 1];
    #pragma unroll
    for (int c = 0; c < 8; ++c){
      acc[c]     = b2f((unsigned short)xh0[c]) + b2f((unsigned short)xl0[c]);
      acc[8 + c] = b2f((unsigned short)xh1[c]) + b2f((unsigned short)xl1[c]);
    }
    int e = offs[row_g];
    int end = e + counts[row_g];
    for (; e + 4 <= end; e += 4){
      int s0 = csr_src[e], s1 = csr_src[e + 1], s2 = csr_src[e + 2], s3 = csr_src[e + 3];
      short8 a0 = H8[s0 * 16 + p * 2], b0 = H8[s0 * 16 + p * 2 + 1];
      short8 a1 = H8[s1 * 16 + p * 2], b1 = H8[s1 * 16 + p * 2 + 1];
      short8 a2 = H8[s2 * 16 + p * 2], b2 = H8[s2 * 16 + p * 2 + 1];
      short8 a3 = H8[s3 * 16 + p * 2], b3 = H8[s3 * 16 + p * 2 + 1];
      #pragma unroll
      for (int c = 0; c < 8; ++c){
        acc[c]     += b2f((unsigned short)a0[c]) + b2f((unsigned short)a1[c])
                    + b2f((unsigned short)a2[c]) + b2f((unsigned short)a3[c]);
        acc[8 + c] += b2f((unsigned short)b0[c]) + b2f((unsigned short)b1[c])
                    + b2f((unsigned short)b2[c]) + b2f((unsigned short)b3[c]);
      }
    }
    for (; e < end; ++e){
      int s0 = csr_src[e];
      short8 a0 = H8[s0 * 16 + p * 2], b0 = H8[s0 * 16 + p * 2 + 1];
      #pragma unroll
      for (int c = 0; c < 8; ++c){
        acc[c]     += b2f((unsigned short)a0[c]);
        acc[8 + c] += b2f((unsigned short)b0[c]);
      }
    }
    short8 oh0, ol0, oh1, ol1;
    #pragma unroll
    for (int c = 0; c < 8; ++c){
      unsigned short h0 = f2b(acc[c]);
      oh0[c] = (short)h0; ol0[c] = (short)f2b(acc[c] - b2f(h0));
      unsigned short h1 = f2b(acc[8 + c]);
      oh1[c] = (short)h1; ol1[c] = (short)f2b(acc[8 + c] - b2f(h1));
    }
    *(short8*)&Ahi_s[row_l * LSTR + p * 16]     = oh0;
    *(short8*)&Ahi_s[row_l * LSTR + p * 16 + 8] = oh1;
    *(short8*)&Alo_s[row_l * LSTR + p * 16]     = ol0;
    *(short8*)&Alo_s[row_l * LSTR + p * 16 + 8] = ol1;
  }
  __syncthreads();   // A ready

  int wave = t >> 6, lane = t & 63, l16 = lane & 15, q = lane >> 4;
  int r0 = (wave >> 1) * 16;     // block-local tile rows
  int c0 = (wave & 1) * 64;      // tile cols
  const short8* B1H = (const short8*)W1h;   // [j][16]
  const short8* B1L = (const short8*)W1l;
  const short8* B2H = (const short8*)W2h;
  const short8* B2L = (const short8*)W2l;

  // ---- phase 2: gemm1 (reads A from LDS, W1 from global/L2) ----
  f32x4 acc[4];
  #pragma unroll
  for (int ct = 0; ct < 4; ++ct) acc[ct] = (f32x4){0.f, 0.f, 0.f, 0.f};
  #pragma unroll
  for (int kc = 0; kc < 4; ++kc){
    short8 ah = *(const short8*)&Ahi_s[(r0 + l16) * LSTR + kc * 32 + q * 8];
    short8 al = *(const short8*)&Alo_s[(r0 + l16) * LSTR + kc * 32 + q * 8];
    #pragma unroll
    for (int ct = 0; ct < 4; ++ct){
      int wr = c0 + ct * 16 + l16;
      short8 bh = B1H[wr * 16 + kc * 4 + q];
      short8 bl = B1L[wr * 16 + kc * 4 + q];
      acc[ct] = __builtin_amdgcn_mfma_f32_16x16x32_bf16(ah, bh, acc[ct], 0, 0, 0);
      acc[ct] = __builtin_amdgcn_mfma_f32_16x16x32_bf16(ah, bl, acc[ct], 0, 0, 0);
      acc[ct] = __builtin_amdgcn_mfma_f32_16x16x32_bf16(al, bh, acc[ct], 0, 0, 0);
    }
  }
  __syncthreads();   // all waves done reading A; A region reusable for H

  // ---- BN1 + ReLU -> write H into A region ----
  #pragma unroll
  for (int ct = 0; ct < 4; ++ct){
    int col = c0 + ct * 16 + l16;
    float s = sc1[col], b = sh1[col];
    #pragma unroll
    for (int r = 0; r < 4; ++r){
      int rl = r0 + q * 4 + r;     // C/D layout: row=(lane>>4)*4+reg
      float v = fmaxf(fmaf(acc[ct][r], s, b), 0.f);
      unsigned short h = f2b(v);
      Ahi_s[rl * LSTR + col] = h;
      Alo_s[rl * LSTR + col] = f2b(v - b2f(h));
    }
  }
  __syncthreads();   // H ready

  // ---- phase 3: gemm2 ----
  f32x4 acc2[4];
  #pragma unroll
  for (int ct = 0; ct < 4; ++ct) acc2[ct] = (f32x4){0.f, 0.f, 0.f, 0.f};
  #pragma unroll
  for (int kc = 0; kc < 4; ++kc){
    short8 ah = *(const short8*)&Ahi_s[(r0 + l16) * LSTR + kc * 32 + q * 8];
    short8 al = *(const short8*)&Alo_s[(r0 + l16) * LSTR + kc * 32 + q * 8];
    #pragma unroll
    for (int ct = 0; ct < 4; ++ct){
      int wr = c0 + ct * 16 + l16;
      short8 bh = B2H[wr * 16 + kc * 4 + q];
      short8 bl = B2L[wr * 16 + kc * 4 + q];
      acc2[ct] = __builtin_amdgcn_mfma_f32_16x16x32_bf16(ah, bh, acc2[ct], 0, 0, 0);
      acc2[ct] = __builtin_amdgcn_mfma_f32_16x16x32_bf16(ah, bl, acc2[ct], 0, 0, 0);
      acc2[ct] = __builtin_amdgcn_mfma_f32_16x16x32_bf16(al, bh, acc2[ct], 0, 0, 0);
    }
  }
  __syncthreads();   // all waves done reading H; region reusable for staging

  // ---- epilogue: BN2 + ReLU; stage (wave-private subtile), coalesced store ----
  if (!LAST){
    #pragma unroll
    for (int ct = 0; ct < 4; ++ct){
      int col = c0 + ct * 16 + l16;
      float s = sc2[col], b = sh2[col];
      #pragma unroll
      for (int r = 0; r < 4; ++r){
        int rl = r0 + q * 4 + r;
        float v = fmaxf(fmaf(acc2[ct][r], s, b), 0.f);
        unsigned short h = f2b(v);
        Ahi_s[rl * LSTR + col] = h;
        Alo_s[rl * LSTR + col] = f2b(v - b2f(h));
      }
    }
    // wave-private readback (own 16 rows x 64 cols): no barrier needed
    int rr = lane >> 3, ch = lane & 7;
    #pragma unroll
    for (int i = 0; i < 2; ++i){
      int rl = r0 + i * 8 + rr;
      int rg = base + rl;
      short8 vh = *(const short8*)&Ahi_s[rl * LSTR + c0 + ch * 8];
      short8 vl = *(const short8*)&Alo_s[rl * LSTR + c0 + ch * 8];
      if (rg < NN){
        *(short8*)&Ohi[rg * DD + c0 + ch * 8] = vh;
        *(short8*)&Olo[rg * DD + c0 + ch * 8] = vl;
      }
    }
  } else {
    float* Cf = (float*)smem;      // 32 x 132 floats = 16,896 B (fits)
    #pragma unroll
    for (int ct = 0; ct < 4; ++ct){
      int col = c0 + ct * 16 + l16;
      float s = sc2[col], b = sh2[col];
      #pragma unroll
      for (int r = 0; r < 4; ++r){
        int rl = r0 + q * 4 + r;
        Cf[rl * 132 + col] = fmaxf(fmaf(acc2[ct][r], s, b), 0.f);
      }
    }
    int rr = lane >> 4, cf = (lane & 15) * 4;
    #pragma unroll
    for (int i = 0; i < 4; ++i){
      int rl = r0 + i * 4 + rr;
      int rg = base + rl;
      float4 v = *(const float4*)&Cf[rl * 132 + c0 + cf];
      if (rg < NN) *(float4*)&Of[rg * DD + c0 + cf] = v;
    }
  }
}

// ---------- launch ----------
extern "C" void kernel_launch(void* const* d_in, const int* in_sizes, int n_in,
                              void* d_out, int out_size, void* d_ws, size_t ws_size,
                              hipStream_t stream) {
  const float* x  = (const float*)d_in[0];
  const int* ei   = (const int*)d_in[1];
  const float* W1 = (const float*)d_in[2];
  const float* b1 = (const float*)d_in[3];
  const float* W2 = (const float*)d_in[4];
  const float* b2 = (const float*)d_in[5];
  const float* g  = (const float*)d_in[6];
  const float* be = (const float*)d_in[7];
  const float* rm = (const float*)d_in[8];
  const float* rv = (const float*)d_in[9];

  const int* src = ei;
  const int* dst = ei + NE;

  char* w = (char*)d_ws;
  const size_t HB = (size_t)NN * DD * sizeof(unsigned short);  // 12.8 MB
  unsigned short* S0hi = (unsigned short*)w; w += HB;
  unsigned short* S0lo = (unsigned short*)w; w += HB;
  unsigned short* S1hi = (unsigned short*)w; w += HB;
  unsigned short* S1lo = (unsigned short*)w; w += HB;
  unsigned short* Wthi = (unsigned short*)w; w += 6 * 16384 * sizeof(unsigned short);
  unsigned short* Wtlo = (unsigned short*)w; w += 6 * 16384 * sizeof(unsigned short);
  float* scv = (float*)w; w += NL * 2 * DD * sizeof(float);
  float* shv = (float*)w; w += NL * 2 * DD * sizeof(float);
  int* counts  = (int*)w; w += 200192;
  int* offs    = (int*)w; w += 200192;
  int* blkhist = (int*)w; w += MH * sizeof(int);
  int* pos     = (int*)w; w += MH * sizeof(int);
  int* bsum    = (int*)w; w += 1024;
  unsigned int* binned = (unsigned int*)w; w += (size_t)NE * sizeof(unsigned int);
  int* csr_src = (int*)w; w += (size_t)NE * sizeof(int);

  // CSR build: deterministic two-level binning (no cross-XCD line sharing)
  const int SCAN_BLK = (MH + 255) / 256;   // 154
  k_hist<<<NB_E, 256, 0, stream>>>(dst, blkhist);
  k_scanA<<<SCAN_BLK, 256, 0, stream>>>(blkhist, pos, bsum, MH);
  k_scanB<<<1, 256, 0, stream>>>(bsum, SCAN_BLK);
  k_scanC<<<SCAN_BLK, 256, 0, stream>>>(pos, bsum, MH);
  k_bin<<<NB_E, 256, 0, stream>>>(src, dst, pos, binned);
  k_csr<<<NBK, 256, 0, stream>>>(binned, pos, offs, counts, csr_src);

  // weight / BN prep + x split
  k_prep_w<<<384, 256, 0, stream>>>(W1, W2, Wthi, Wtlo);
  k_prep_bn<<<3, 256, 0, stream>>>(b1, b2, g, be, rm, rv, scv, shv);
  k_cvt<<<NN * DD / 8 / 256, 256, 0, stream>>>(x, S0hi, S0lo);

  const int LAYER_BLOCKS = (NN + 31) / 32;   // 1563

  for (int i = 0; i < NL; ++i){
    const unsigned short* W1h = Wthi + (size_t)(i * 2 + 0) * 16384;
    const unsigned short* W1l = Wtlo + (size_t)(i * 2 + 0) * 16384;
    const unsigned short* W2h = Wthi + (size_t)(i * 2 + 1) * 16384;
    const unsigned short* W2l = Wtlo + (size_t)(i * 2 + 1) * 16384;
    const float* sc1 = scv + (size_t)(i * 2 + 0) * DD;
    const float* sh1 = shv + (size_t)(i * 2 + 0) * DD;
    const float* sc2 = scv + (size_t)(i * 2 + 1) * DD;
    const float* sh2 = shv + (size_t)(i * 2 + 1) * DD;

    const unsigned short* Ih = (i & 1) ? S1hi : S0hi;
    const unsigned short* Il = (i & 1) ? S1lo : S0lo;
    unsigned short* Oh = (i & 1) ? S0hi : S1hi;
    unsigned short* Ol = (i & 1) ? S0lo : S1lo;

    if (i == NL - 1){
      k_layer<1><<<LAYER_BLOCKS, 256, 0, stream>>>(Ih, Il, offs, counts, csr_src,
          W1h, W1l, W2h, W2l, sc1, sh1, sc2, sh2,
          (unsigned short*)nullptr, (unsigned short*)nullptr, (float*)d_out);
    } else {
      k_layer<0><<<LAYER_BLOCKS, 256, 0, stream>>>(Ih, Il, offs, counts, csr_src,
          W1h, W1l, W2h, W2l, sc1, sh1, sc2, sh2, Oh, Ol, (float*)nullptr);
    }
  }
}